// Round 4
// baseline (765.897 us; speedup 1.0000x reference)
//
#include <hip/hip_runtime.h>

// Sub_MGU: B=64, T=2048, S=32, H=16. 2048 independent serial sequences.
//
// R6 change vs R5 (dispatch 361us = 423 cyc/step, VALUBusy 32.6% -> 138 cyc
// issue + ~285 cyc stall; 1 wave/SIMD so the serial nonlinear chain
// (add-tree -> exp2 -> rcp -> fma -> exp2 -> rcp -> fma -> fma -> DPP) is
// fully exposed by in-order issue):
//  - 2-way TEMPORAL INTERLEAVE: each wave now owns TWO independent cells per
//    16-lane group (same subunit s -> shared weight regs; batches b and
//    b+32). Stream B's instructions fill stream A's dependency stalls and
//    vice versa. Grid 512 -> 256 blocks. Per step-pair issue ~276 cyc vs
//    chain ~285 cyc -> ~150 cyc per effective step.
// Carried from R5: opaque store snapshots (16-deep, kills per-step store
// WAR vmcnt drain), 16-deep x prefetch ring, 4-way split FMA chains.
// Carried from R3: DPP row_ror h-exchange, exp2 scales folded into
// weights/biases, omh = 1-h off the critical path.

#define TT 2048
#define SS 32
#define HH 16

// DPP row_ror:R within each 16-lane row. ctrl = 0x120 + R (R>=1).
template <int R>
__device__ __forceinline__ void bcast_ror(int hi, float* u) {
    u[R] = __int_as_float(
        __builtin_amdgcn_update_dpp(hi, hi, 0x120 + R, 0xF, 0xF, false));
    if constexpr (R + 1 < 16) bcast_ror<R + 1>(hi, u);
}

// Same network applied to an integer lane-id probe: k[r] = source lane of
// slot r (direction-proof weight permutation discovery).
template <int R>
__device__ __forceinline__ void probe_ror(int jj, int* k) {
    k[R] = __builtin_amdgcn_update_dpp(jj, jj, 0x120 + R, 0xF, 0xF, false);
    if constexpr (R + 1 < 16) probe_ror<R + 1>(jj, k);
}

template <bool REFILL>
__device__ __forceinline__ void block16_dual(
    float (&h)[2], float (&omh)[2],
    float (&xb0)[16], float (&xb1)[16],
    const float* xq0, const float* xq1,
    float* op0, float* op1,
    const float (&wf)[16], const float (&wn)[16],
    float wifp, float winp, float bfp, float binp, float bhnp)
{
    float hs0[16], hs1[16];
#pragma unroll
    for (int p = 0; p < 16; ++p) {
        const float x0 = xb0[p];
        const float x1 = xb1[p];
        if constexpr (REFILL) {          // refill for step q+16
            xb0[p] = xq0[p * SS];
            xb1[p] = xq1[p * SS];
        }

        // ---- h exchange: 15x DPP row_ror per stream (VALU pipe) ----
        float u[2][16];
        u[0][0] = h[0];
        u[1][0] = h[1];
        bcast_ror<1>(__float_as_int(h[0]), u[0]);
        bcast_ror<1>(__float_as_int(h[1]), u[1]);

        const float xx[2] = {x0, x1};
        float accf[2], accn[2];
#pragma unroll
        for (int i = 0; i < 2; ++i) {
            // dual matvecs, 4-way split: 8 independent 4-deep FMA chains
            float a0 = __builtin_fmaf(xx[i], wifp, bfp), a1 = 0.f, a2 = 0.f, a3 = 0.f;
            float c0 = bhnp, c1 = 0.f, c2 = 0.f, c3 = 0.f;
#pragma unroll
            for (int kk = 0; kk < 4; ++kk) {
                a0 = __builtin_fmaf(wf[4*kk+0], u[i][4*kk+0], a0);
                a1 = __builtin_fmaf(wf[4*kk+1], u[i][4*kk+1], a1);
                a2 = __builtin_fmaf(wf[4*kk+2], u[i][4*kk+2], a2);
                a3 = __builtin_fmaf(wf[4*kk+3], u[i][4*kk+3], a3);
                c0 = __builtin_fmaf(wn[4*kk+0], u[i][4*kk+0], c0);
                c1 = __builtin_fmaf(wn[4*kk+1], u[i][4*kk+1], c1);
                c2 = __builtin_fmaf(wn[4*kk+2], u[i][4*kk+2], c2);
                c3 = __builtin_fmaf(wn[4*kk+3], u[i][4*kk+3], c3);
            }
            accf[i] = (a0 + a1) + (a2 + a3);  // -log2e * forget preact
            accn[i] = (c0 + c1) + (c2 + c3);  // 2log2e * recurrent new preact
        }

#pragma unroll
        for (int i = 0; i < 2; ++i) {
            // f = sigmoid = rcp(1+exp2(accf)); n = tanh = 1 - 2*rcp(1+exp2(y))
            const float f   = __builtin_amdgcn_rcpf(1.0f + __builtin_amdgcn_exp2f(accf[i]));
            const float inp = __builtin_fmaf(xx[i], winp, binp);
            const float y   = __builtin_fmaf(f, accn[i], inp);
            const float rr  = __builtin_amdgcn_rcpf(1.0f + __builtin_amdgcn_exp2f(y));
            const float nmh = __builtin_fmaf(-2.0f, rr, omh[i]);  // n - h
            h[i]   = __builtin_fmaf(f, nmh, h[i]);                // h += f*(n-h)
            omh[i] = 1.0f - h[i];
        }

        // Opaque snapshots: store-data regs are NOT the recurrence regs.
        asm volatile("v_mov_b32 %0, %1" : "=v"(hs0[p]) : "v"(h[0]));
        asm volatile("v_mov_b32 %0, %1" : "=v"(hs1[p]) : "v"(h[1]));
        op0[(size_t)p * (SS * HH)] = hs0[p];
        op1[(size_t)p * (SS * HH)] = hs1[p];
    }
    // Keep store-data registers live to block end: each physreg is redefined
    // only one full block (16 steps) after its store read it -> no WAR drain.
    asm volatile("" ::
        "v"(hs0[0]),  "v"(hs0[1]),  "v"(hs0[2]),  "v"(hs0[3]),
        "v"(hs0[4]),  "v"(hs0[5]),  "v"(hs0[6]),  "v"(hs0[7]),
        "v"(hs0[8]),  "v"(hs0[9]),  "v"(hs0[10]), "v"(hs0[11]),
        "v"(hs0[12]), "v"(hs0[13]), "v"(hs0[14]), "v"(hs0[15]));
    asm volatile("" ::
        "v"(hs1[0]),  "v"(hs1[1]),  "v"(hs1[2]),  "v"(hs1[3]),
        "v"(hs1[4]),  "v"(hs1[5]),  "v"(hs1[6]),  "v"(hs1[7]),
        "v"(hs1[8]),  "v"(hs1[9]),  "v"(hs1[10]), "v"(hs1[11]),
        "v"(hs1[12]), "v"(hs1[13]), "v"(hs1[14]), "v"(hs1[15]));
}

__global__ __launch_bounds__(64) void mgu_kernel(
    const float* __restrict__ input,   // [B, T, S]
    const float* __restrict__ W_hif,   // [S, H]
    const float* __restrict__ W_hin,   // [S, H]
    const float* __restrict__ W_hhf,   // [S, H, H]
    const float* __restrict__ W_hhn,   // [S, H, H]
    const float* __restrict__ bias_hi, // [2*S*H]
    const float* __restrict__ bias_hh, // [2*S*H]
    float* __restrict__ out)           // [B, T, S*H]
{
    const int lane = threadIdx.x;      // 0..63
    const int sl   = lane >> 4;        // cell within wave (0..3)
    const int j    = lane & 15;
    const int bA   = blockIdx.x & 31;  // stream-A batch
    const int bB   = bA + 32;          // stream-B batch (same s -> shared weights)
    const int sg   = blockIdx.x >> 5;  // subunit group (0..7)
    const int s    = sg * 4 + sl;      // subunit (0..31)
    const int row  = s * HH + j;

    const float NL2E = -1.442695041f;  // -log2(e)
    const float TL2E =  2.885390082f;  // 2*log2(e)

    // ---- discover the DPP ror lane->slot mapping ----
    int kidx[16];
    kidx[0] = j;
    probe_ror<1>(j, kidx);

    // ---- preload weight rows, permuted to DPP slot order, scales folded ----
    float wf[16], wn[16];
    {
        const float* Wfr = W_hhf + row * HH;
        const float* Wnr = W_hhn + row * HH;
#pragma unroll
        for (int r = 0; r < 16; ++r) {
            wf[r] = Wfr[kidx[r]] * NL2E;
            wn[r] = Wnr[kidx[r]] * TL2E;
        }
    }
    const float wifp = W_hif[row] * NL2E;
    const float winp = W_hin[row] * TL2E;
    const float bfp  = (bias_hi[row] + bias_hh[row]) * NL2E;  // folded forget biases
    const float binp = bias_hi[SS * HH + row] * TL2E;
    const float bhnp = bias_hh[SS * HH + row] * TL2E;

    const float* xpA = input + (size_t)bA * (TT * SS) + s;
    const float* xpB = input + (size_t)bB * (TT * SS) + s;
    float*       opA = out   + (size_t)bA * (TT * SS * HH) + sg * 64 + lane;
    float*       opB = out   + (size_t)bB * (TT * SS * HH) + sg * 64 + lane;

    // ---- 16-deep x prefetch rings (one per stream) ----
    float xbA[16], xbB[16];
#pragma unroll
    for (int i = 0; i < 16; ++i) {
        xbA[i] = xpA[i * SS];
        xbB[i] = xpB[i * SS];
    }

    float h[2]   = {0.0f, 0.0f};
    float omh[2] = {1.0f, 1.0f};   // 1 - h, maintained off critical path

#pragma unroll 1
    for (int t = 0; t < TT - 16; t += 16) {
        block16_dual<true>(h, omh, xbA, xbB,
                           xpA + (size_t)(t + 16) * SS,
                           xpB + (size_t)(t + 16) * SS,
                           opA + (size_t)t * (SS * HH),
                           opB + (size_t)t * (SS * HH),
                           wf, wn, wifp, winp, bfp, binp, bhnp);
    }
    // Tail: last 16 steps consume the rings, no refill.
    block16_dual<false>(h, omh, xbA, xbB,
                        xpA, xpB,  // unused
                        opA + (size_t)(TT - 16) * (SS * HH),
                        opB + (size_t)(TT - 16) * (SS * HH),
                        wf, wn, wifp, winp, bfp, binp, bhnp);
}

extern "C" void kernel_launch(void* const* d_in, const int* in_sizes, int n_in,
                              void* d_out, int out_size, void* d_ws, size_t ws_size,
                              hipStream_t stream) {
    const float* input   = (const float*)d_in[0];
    const float* W_hif   = (const float*)d_in[1];
    const float* W_hin   = (const float*)d_in[2];
    const float* W_hhf   = (const float*)d_in[3];
    const float* W_hhn   = (const float*)d_in[4];
    const float* bias_hi = (const float*)d_in[5];
    const float* bias_hh = (const float*)d_in[6];
    float* out = (float*)d_out;

    mgu_kernel<<<dim3(256), dim3(64), 0, stream>>>(
        input, W_hif, W_hin, W_hhf, W_hhn, bias_hi, bias_hh, out);
}